// Round 13
// baseline (1287.520 us; speedup 1.0000x reference)
//
#include <hip/hip_runtime.h>
#include <math.h>

// B=4096, L=64, H=64, V=21, NH=4, HD=16, FF=128, NL=2
constexpr int BATCH = 4096;

typedef float v2f __attribute__((ext_vector_type(2)));
// packed fp32 FMA: acc = a*w + acc (2 lanes-halves per instruction)
#define PKFMA(acc, a, w) asm("v_pk_fma_f32 %0, %1, %2, %0" : "+v"(acc) : "v"(a), "v"(w))
__device__ __forceinline__ v2f dup2(float x) { v2f r; r[0] = x; r[1] = x; return r; }

// ---------------- LDS regions (float indices), total 39,168 B -> 4 blocks/CU
constexpr int A    = 0;
constexpr int B0   = 4352;
constexpr int PS   = B0 + 4096;     // 4x64 LN partial sums
constexpr int PSQ  = PS + 256;      // 4x64 LN partial sumsq
constexpr int HOPB = PS;            // head: hop[r][4] reuses dead PS region
constexpr int MB   = 9024;
constexpr int M_MASK = MB + 0;
constexpr int M_DVAL = MB + 64;
constexpr int M_ISD  = MB + 128;
constexpr int M_SD   = MB + 192;    // final rw
constexpr int M_DG   = MB + 320;    // scalars
constexpr int M_DVEC = MB + 384;    // g diagonal
constexpr int M_S    = MB + 448;    // prefix sums (log2 units)
constexpr int M_PRU  = MB + 512;    // prior g[i,i+1]
constexpr int M_PRD  = MB + 576;    // prior g[i,i]
constexpr int M_SU   = MB + 640;    // final scores
constexpr int LDSN   = MB + 768;    // 9792 floats = 39,168 B

// ---------------- output layout (floats) ----------------
constexpr int O_RES   = 0;
constexpr int O_REMB  = 4096;
constexpr int O_VALID = 266240;
constexpr int O_LEFT  = 270336;
constexpr int O_RIGHT = 274432;
constexpr int O_OPL   = 278528;
constexpr int O_RW    = 294912;

#define LN_PART() do {                                                    \
    float s_ = 0.f, q_ = 0.f;                                             \
    _Pragma("unroll") for (int j = 0; j < 16; ++j) {                      \
        s_ += xr[j]; q_ = fmaf(xr[j], xr[j], q_); }                       \
    lds[PS  + (wv << 6) + lane] = s_;                                     \
    lds[PSQ + (wv << 6) + lane] = q_;                                     \
} while (0)

#define LN_APPLY(GPTR, BPTR) do {                                         \
    float fs_ = lds[PS + lane] + lds[PS + 64 + lane]                      \
              + lds[PS + 128 + lane] + lds[PS + 192 + lane];              \
    float fq_ = lds[PSQ + lane] + lds[PSQ + 64 + lane]                    \
              + lds[PSQ + 128 + lane] + lds[PSQ + 192 + lane];            \
    float mu_ = fs_ * 0.015625f;                                          \
    float inv_ = rsqrtf(fq_ * 0.015625f - mu_ * mu_ + 1e-6f);             \
    _Pragma("unroll") for (int j = 0; j < 16; ++j) {                      \
        int c_ = c0 + j;                                                  \
        lds[A + c_ * 64 + lane] =                                         \
            (xr[j] - mu_) * inv_ * (GPTR)[c_] + (BPTR)[c_];               \
    }                                                                     \
} while (0)

__global__ void __launch_bounds__(256, 4) fsa_kernel(
    const int* __restrict__ tok,
    const float* __restrict__ emb, const float* __restrict__ np_w, const float* __restrict__ np_b,
    const float* __restrict__ grp_wq, const float* __restrict__ grp_bq,
    const float* __restrict__ grp_wk, const float* __restrict__ grp_bk,
    const float* __restrict__ grp_ln_g, const float* __restrict__ grp_ln_b,
    const float* __restrict__ attn_w, const float* __restrict__ attn_b,
    const float* __restrict__ ln1_g, const float* __restrict__ ln1_b,
    const float* __restrict__ ln2_g, const float* __restrict__ ln2_b,
    const float* __restrict__ ffn_w1, const float* __restrict__ ffn_b1,
    const float* __restrict__ ffn_w2, const float* __restrict__ ffn_b2,
    const float* __restrict__ enc_g, const float* __restrict__ enc_b,
    const float* __restrict__ red_w, const float* __restrict__ red_b,
    const float* __restrict__ opc_w, const float* __restrict__ opc_b,
    const float* __restrict__ res_w, const float* __restrict__ res_b,
    float* __restrict__ out)
{
    __shared__ __align__(16) float lds[LDSN];
    const int b = blockIdx.x;
    const int tid = threadIdx.x;
    const int lane = tid & 63;
    const int wv = __builtin_amdgcn_readfirstlane(tid >> 6);
    const int c0 = wv << 4;
    float xr[16];                 // x[lane][c0 .. c0+15] in registers

    // ================= embedding + positional encoding =================
    {
        int t = tok[(b << 6) + lane];
        float mk  = (t != 0) ? 1.f : 0.f;
        float isd = (t >= 4 && t <= 13) ? 1.f : 0.f;
        float dvv = ((float)t - 4.f) * isd;
        float iso = (t >= 14 && t <= 17) ? 1.f : 0.f;
        float opt = iso * ((float)t - 13.f);
        if (wv == 0) {
            lds[M_MASK + lane] = mk;  lds[M_DVAL + lane] = dvv; lds[M_ISD + lane] = isd;
            lds[M_PRU + lane] = 0.f;  lds[M_PRD + lane] = 0.f;
        }
        const float lg = -0.143911568f;   // -ln(10000)/64
        #pragma unroll
        for (int j = 0; j < 16; ++j) {
            int c = c0 + j;
            float freq = expf((float)(c & ~1) * lg);
            float ang = (float)lane * freq;
            float pe = (c & 1) ? cosf(ang) : sinf(ang);
            xr[j] = emb[t * 64 + c] * 8.f
                  + dvv * np_w[c] + isd * np_w[64 + c]
                  + opt * np_w[128 + c] + iso * np_w[192 + c]
                  + np_b[c] + pe;
        }
        LN_PART();                // partials for first gLN
    }
    __syncthreads();
    const unsigned long long mall = __ballot(lds[M_MASK + lane] > 0.f);

    // ================= transformer layers =================
    for (int il = 0; il < 2; ++il) {
        const float* gwq = grp_wq + il * 4096; const float* gbq = grp_bq + (il << 6);
        const float* gwk = grp_wk + il * 4096; const float* gbk = grp_bk + (il << 6);
        const float* glg = grp_ln_g + (il << 6); const float* glb = grp_ln_b + (il << 6);
        const float* aw  = attn_w + il * 16384;  const float* ab  = attn_b + (il << 8);
        const float* l1g = ln1_g + (il << 6);    const float* l1b = ln1_b + (il << 6);
        const float* l2g = ln2_g + (il << 6);    const float* l2b = ln2_b + (il << 6);
        const float* fw1 = ffn_w1 + il * 8192;   const float* fb1 = ffn_b1 + (il << 7);
        const float* fw2 = ffn_w2 + il * 8192;   const float* fb2 = ffn_b2 + (il << 6);

        // ---- group attention: fused gQ/gK GEMM + in-register adjacent dots ----
        LN_APPLY(glg, glb);               // h -> A (hT)
        __syncthreads();
        {
            v2f qa[8], ka[8];
            const v2f* gbq2 = reinterpret_cast<const v2f*>(gbq + c0);
            const v2f* gbk2 = reinterpret_cast<const v2f*>(gbk + c0);
            #pragma unroll
            for (int j = 0; j < 8; ++j) { qa[j] = gbq2[j]; ka[j] = gbk2[j]; }
            #pragma unroll 8
            for (int kk = 0; kk < 64; ++kk) {
                v2f a2 = dup2(lds[A + kk * 64 + lane]);
                const v2f* wq2 = reinterpret_cast<const v2f*>(gwq + kk * 64 + c0);
                const v2f* wk2 = reinterpret_cast<const v2f*>(gwk + kk * 64 + c0);
                #pragma unroll
                for (int j = 0; j < 8; ++j) {
                    PKFMA(qa[j], a2, wq2[j]);
                    PKFMA(ka[j], a2, wk2[j]);
                }
            }
            // adjacent-pair partial dots over this wave's 16-col slice
            v2f su2 = dup2(0.f), sd2 = dup2(0.f);
            #pragma unroll
            for (int j = 0; j < 8; ++j) {
                v2f kn, qn;
                kn[0] = __shfl_down(ka[j][0], 1); kn[1] = __shfl_down(ka[j][1], 1);
                qn[0] = __shfl_down(qa[j][0], 1); qn[1] = __shfl_down(qa[j][1], 1);
                PKFMA(su2, qa[j], kn);
                PKFMA(sd2, qn, ka[j]);
            }
            lds[B0 + (wv << 6) + lane] = su2[0] + su2[1];
            lds[B0 + 256 + (wv << 6) + lane] = sd2[0] + sd2[1];
            LN_PART();                              // LN1 partials (PS region)
        }
        __syncthreads();

        // scan (wave0); other waves idle one short phase
        if (wv == 0) {
            const int i = lane;
            float su = (lds[B0 + i] + lds[B0 + 64 + i]
                      + lds[B0 + 128 + i] + lds[B0 + 192 + i]) * 0.125f;
            float sdv = (lds[B0 + 256 + i] + lds[B0 + 320 + i]
                       + lds[B0 + 384 + i] + lds[B0 + 448 + i]) * 0.125f;
            float sd_im1 = __shfl_up(sdv, 1);     // s[i,i-1]
            float mi  = lds[M_MASK + i];
            float mup = (i < 63) ? lds[M_MASK + i + 1] : 0.f;
            float mdn = (i > 0)  ? lds[M_MASK + i - 1] : 0.f;
            float eu = (i < 63 && mi > 0.f && mup > 0.f) ? su : -1e9f;
            float ed = (i > 0 && mi > 0.f && mdn > 0.f) ? sd_im1 : -1e9f;
            float m = fmaxf(eu, ed);
            float nu, nd, ng;
            if (m <= -1e9f) { nu = 0.015625f; nd = 0.015625f; ng = 0.015625f; }
            else {
                float zu = __expf(eu - m), zd = __expf(ed - m);
                float iz = 1.f / (zu + zd);
                nu = zu * iz; nd = zd * iz; ng = 0.f;
            }
            float nd1 = __shfl_down(nd, 1);       // nb_dn of row i+1
            float pd = lds[M_PRD + i];
            float dsym = sqrtf(ng * ng + 1e-9f);
            float d2 = pd + (1.f - pd) * dsym;
            lds[M_DVEC + i] = d2; lds[M_PRD + i] = d2;
            float la2 = 0.f;                      // log2 units
            if (i < 63) {
                float pu = lds[M_PRU + i];
                float as_ = sqrtf(nu * nd1 + 1e-9f);
                float a2v = pu + (1.f - pu) * as_;
                la2 = __log2f(a2v + 1e-9f);
                lds[M_PRU + i] = exp2f(la2) + 1e-9f;   // next-layer prior
            }
            float x = __shfl_up(la2, 1);
            if (i == 0) x = 0.f;
            #pragma unroll
            for (int off = 1; off < 64; off <<= 1) {
                float t2 = __shfl_up(x, off);
                if (i >= off) x += t2;
            }
            lds[M_S + i] = x;                     // S2[i] = log2 prefix sums
        }
        __syncthreads();

        // ---- MHA: wave wv owns head wv; lane owns row=lane; JIT K/V tiles ----
        LN_APPLY(l1g, l1b);               // h -> A
        __syncthreads();
        {
            const int hb = wv << 4;
            const int TB = B0 + wv * 640;      // wave-local K(16x20) + V(16x20) tile
            const int jl = lane & 15, cq = lane >> 4;
            const float SCL = 0.36067376f;     // 0.25 * log2(e)
            v2f qa[8];
            const v2f* ab2 = reinterpret_cast<const v2f*>(ab + hb);
            #pragma unroll
            for (int j = 0; j < 8; ++j) qa[j] = ab2[j];
            #pragma unroll 8
            for (int kk = 0; kk < 64; ++kk) {
                v2f a2 = dup2(lds[A + kk * 64 + lane]);
                const v2f* wq2 = reinterpret_cast<const v2f*>(aw + kk * 64 + hb);
                #pragma unroll
                for (int j = 0; j < 8; ++j) PKFMA(qa[j], a2, wq2[j]);
            }
            const float Sr2 = lds[M_S + lane];
            const float dvr = lds[M_DVEC + lane];
            v2f o2[8];
            #pragma unroll
            for (int c = 0; c < 8; ++c) o2[c] = dup2(0.f);
            float mrun = -1e30f, z = 0.f;
            for (int jt = 0; jt < 4; ++jt) {
                {   // JIT K/V tile: rows jt*16+jl, cols hb+cq*4..+3 (wave-local)
                    v2f kacc[2], vacc[2];
                    const v2f* kb2 = reinterpret_cast<const v2f*>(ab + 64 + hb + (cq << 2));
                    const v2f* vb2 = reinterpret_cast<const v2f*>(ab + 128 + hb + (cq << 2));
                    kacc[0] = kb2[0]; kacc[1] = kb2[1];
                    vacc[0] = vb2[0]; vacc[1] = vb2[1];
                    const int row = (jt << 4) + jl;
                    #pragma unroll 8
                    for (int kk = 0; kk < 64; ++kk) {
                        v2f a2 = dup2(lds[A + kk * 64 + row]);
                        const v2f* wk2  = reinterpret_cast<const v2f*>(aw + 4096 + kk * 64 + hb + (cq << 2));
                        const v2f* wv2  = reinterpret_cast<const v2f*>(aw + 8192 + kk * 64 + hb + (cq << 2));
                        PKFMA(kacc[0], a2, wk2[0]); PKFMA(kacc[1], a2, wk2[1]);
                        PKFMA(vacc[0], a2, wv2[0]); PKFMA(vacc[1], a2, wv2[1]);
                    }
                    *reinterpret_cast<float4*>(&lds[TB + jl * 20 + (cq << 2)]) =
                        make_float4(kacc[0][0], kacc[0][1], kacc[1][0], kacc[1][1]);
                    *reinterpret_cast<float4*>(&lds[TB + 320 + jl * 20 + (cq << 2)]) =
                        make_float4(vacc[0][0], vacc[0][1], vacc[1][0], vacc[1][1]);
                    asm volatile("s_waitcnt lgkmcnt(0)" ::: "memory");  // wave-local fence
                }
                #pragma unroll
                for (int half = 0; half < 2; ++half) {
                    float sc[8]; float tm = -1e30f;
                    #pragma unroll
                    for (int jj = 0; jj < 8; ++jj) {
                        const int jloc = (half << 3) + jj;
                        const int j = (jt << 4) + jloc;
                        v2f s2 = dup2(0.f);
                        #pragma unroll
                        for (int c4 = 0; c4 < 4; ++c4) {
                            const float4 kv = *reinterpret_cast<const float4*>(
                                &lds[TB + jloc * 20 + (c4 << 2)]);
                            v2f klo; klo[0] = kv.x; klo[1] = kv.y;
                            v2f khi; khi[0] = kv.z; khi[1] = kv.w;
                            PKFMA(s2, qa[(c4 << 1)], klo);
                            PKFMA(s2, qa[(c4 << 1) + 1], khi);
                        }
                        float s = s2[0] + s2[1];
                        s = ((mall >> j) & 1ull) ? s * SCL : -1e9f;
                        sc[jj] = s; tm = fmaxf(tm, s);
                    }
                    float mn = fmaxf(mrun, tm);
                    float rs = exp2f(mrun - mn);
                    z *= rs;
                    v2f rs2 = dup2(rs);
                    #pragma unroll
                    for (int c = 0; c < 8; ++c) o2[c] *= rs2;
                    mrun = mn;
                    #pragma unroll
                    for (int jj = 0; jj < 8; ++jj) {
                        const int jloc = (half << 3) + jj;
                        const int j = (jt << 4) + jloc;
                        float e = exp2f(sc[jj] - mn);
                        z += e;
                        float Sj2 = lds[M_S + j];
                        float g = (j == lane) ? dvr
                                  : (exp2f((j > lane) ? (Sj2 - Sr2) : (Sr2 - Sj2)) + 1e-9f);
                        v2f w2 = dup2(e * g);
                        #pragma unroll
                        for (int c4 = 0; c4 < 4; ++c4) {
                            const float4 vv = *reinterpret_cast<const float4*>(
                                &lds[TB + 320 + jloc * 20 + (c4 << 2)]);
                            v2f vlo; vlo[0] = vv.x; vlo[1] = vv.y;
                            v2f vhi; vhi[0] = vv.z; vhi[1] = vv.w;
                            PKFMA(o2[(c4 << 1)], w2, vlo);
                            PKFMA(o2[(c4 << 1) + 1], w2, vhi);
                        }
                    }
                }
            }
            float iz = 1.f / z;
            __syncthreads();          // all waves' h reads done before O overwrites A
            #pragma unroll
            for (int c = 0; c < 8; ++c) {
                lds[A + lane * 65 + hb + (c << 1)]     = o2[c][0] * iz;
                lds[A + lane * 65 + hb + (c << 1) + 1] = o2[c][1] * iz;
            }
            __syncthreads();
            // O-proj: xr += O @ Wo + bo; then LN2 partials (same phase)
            const float* Wo = aw + 12288; const float* bo = ab + 192;
            v2f acc[8];
            const v2f* bo2 = reinterpret_cast<const v2f*>(bo + c0);
            #pragma unroll
            for (int j = 0; j < 8; ++j) acc[j] = bo2[j];
            #pragma unroll 8
            for (int dd = 0; dd < 64; ++dd) {
                v2f a2 = dup2(lds[A + lane * 65 + dd]);
                const v2f* wr2 = reinterpret_cast<const v2f*>(Wo + dd * 64 + c0);
                #pragma unroll
                for (int j = 0; j < 8; ++j) PKFMA(acc[j], a2, wr2[j]);
            }
            #pragma unroll
            for (int j = 0; j < 8; ++j) {
                xr[(j << 1)]     += acc[j][0];
                xr[(j << 1) + 1] += acc[j][1];
            }
            LN_PART();
        }
        __syncthreads();

        // ---- FFN (two 64-col halves of F share one buffer in B0) ----
        LN_APPLY(l2g, l2b);               // h -> A (overwrites O)
        __syncthreads();
        {   // F-lo
            v2f fa[8];
            const v2f* fb2v = reinterpret_cast<const v2f*>(fb1 + c0);
            #pragma unroll
            for (int j = 0; j < 8; ++j) fa[j] = fb2v[j];
            #pragma unroll 8
            for (int kk = 0; kk < 64; ++kk) {
                v2f a2 = dup2(lds[A + kk * 64 + lane]);
                const v2f* wr2 = reinterpret_cast<const v2f*>(fw1 + kk * 128 + c0);
                #pragma unroll
                for (int j = 0; j < 8; ++j) PKFMA(fa[j], a2, wr2[j]);
            }
            #pragma unroll
            for (int j = 0; j < 8; ++j) {
                lds[B0 + (c0 + (j << 1)) * 64 + lane]     = fmaxf(fa[j][0], 0.f);
                lds[B0 + (c0 + (j << 1) + 1) * 64 + lane] = fmaxf(fa[j][1], 0.f);
            }
        }
        __syncthreads();
        {   // xr += F-lo @ W2[0:64]
            v2f acc[8];
            const v2f* fb2v = reinterpret_cast<const v2f*>(fb2 + c0);
            #pragma unroll
            for (int j = 0; j < 8; ++j) acc[j] = fb2v[j];
            #pragma unroll 8
            for (int kk = 0; kk < 64; ++kk) {
                v2f a2 = dup2(lds[B0 + kk * 64 + lane]);
                const v2f* wr2 = reinterpret_cast<const v2f*>(fw2 + kk * 64 + c0);
                #pragma unroll
                for (int j = 0; j < 8; ++j) PKFMA(acc[j], a2, wr2[j]);
            }
            #pragma unroll
            for (int j = 0; j < 8; ++j) {
                xr[(j << 1)]     += acc[j][0];
                xr[(j << 1) + 1] += acc[j][1];
            }
        }
        __syncthreads();
        {   // F-hi
            v2f fa[8];
            const v2f* fb2v = reinterpret_cast<const v2f*>(fb1 + 64 + c0);
            #pragma unroll
            for (int j = 0; j < 8; ++j) fa[j] = fb2v[j];
            #pragma unroll 8
            for (int kk = 0; kk < 64; ++kk) {
                v2f a2 = dup2(lds[A + kk * 64 + lane]);
                const v2f* wr2 = reinterpret_cast<const v2f*>(fw1 + kk * 128 + 64 + c0);
                #pragma unroll
                for (int j = 0; j < 8; ++j) PKFMA(fa[j], a2, wr2[j]);
            }
            #pragma unroll
            for (int j = 0; j < 8; ++j) {
                lds[B0 + (c0 + (j << 1)) * 64 + lane]     = fmaxf(fa[j][0], 0.f);
                lds[B0 + (c0 + (j << 1) + 1) * 64 + lane] = fmaxf(fa[j][1], 0.f);
            }
        }
        __syncthreads();
        {   // xr += F-hi @ W2[64:128]; then next-LN partials (same phase)
            v2f acc[8];
            #pragma unroll
            for (int j = 0; j < 8; ++j) acc[j] = dup2(0.f);
            #pragma unroll 8
            for (int kk = 0; kk < 64; ++kk) {
                v2f a2 = dup2(lds[B0 + kk * 64 + lane]);
                const v2f* wr2 = reinterpret_cast<const v2f*>(fw2 + (64 + kk) * 64 + c0);
                #pragma unroll
                for (int j = 0; j < 8; ++j) PKFMA(acc[j], a2, wr2[j]);
            }
            #pragma unroll
            for (int j = 0; j < 8; ++j) {
                xr[(j << 1)]     += acc[j][0];
                xr[(j << 1) + 1] += acc[j][1];
            }
            LN_PART();                    // for next gLN (or enc LN after last layer)
        }
        __syncthreads();
    }

    // ================= reduction / calculator head =================
    LN_APPLY(enc_g, enc_b);   // final h -> A (hT)
    __syncthreads();
    if (tid < 64) {           // scores + op-logit row dots (shared h reads)
        float s = 0.f, h0 = 0.f, h1 = 0.f, h2 = 0.f, h3 = 0.f;
        #pragma unroll 8
        for (int c2 = 0; c2 < 64; ++c2) {
            float hv = lds[A + c2 * 64 + tid];
            s  = fmaf(hv, red_w[c2], s);
            h0 = fmaf(hv, opc_w[(c2 << 2) + 0], h0);
            h1 = fmaf(hv, opc_w[(c2 << 2) + 1], h1);
            h2 = fmaf(hv, opc_w[(c2 << 2) + 2], h2);
            h3 = fmaf(hv, opc_w[(c2 << 2) + 3], h3);
        }
        s += red_b[0];
        s += (1.f - lds[M_MASK + tid]) * -1e9f;
        lds[M_SU + tid] = s;
        *reinterpret_cast<float4*>(&lds[HOPB + (tid << 2)]) = make_float4(h0, h1, h2, h3);
    }
    __syncthreads();

    if (wv == 0) {        // softmax, scans, digits, op select, scalar outs
        float s = lds[M_SU + lane];
        float m = s;
        #pragma unroll
        for (int off = 1; off < 64; off <<= 1) m = fmaxf(m, __shfl_xor(m, off));
        float ee = expf(s - m);
        float z = ee;
        #pragma unroll
        for (int off = 1; off < 64; off <<= 1) z += __shfl_xor(z, off);
        float rw = ee / z;
        lds[M_SD + lane] = rw;
        float cum = rw;
        #pragma unroll
        for (int off = 1; off < 64; off <<= 1) { float t2 = __shfl_up(cum, off); if (lane >= off) cum += t2; }
        float isd = lds[M_ISD + lane], dvv = lds[M_DVAL + lane];
        float lm = (1.f - cum) * isd;
        float rm = (cum - rw) * isd;
        float cl = lm;
        #pragma unroll
        for (int off = 1; off < 64; off <<= 1) { float t2 = __shfl_up(cl, off); if (lane >= off) cl += t2; }
        float totl = __shfl(cl, 63);
        float wL = powf(10.f, (totl - cl) * lm) * lm;
        float lv = dvv * wL;
        #pragma unroll
        for (int off = 1; off < 64; off <<= 1) lv += __shfl_xor(lv, off);
        float cr = rm;
        #pragma unroll
        for (int off = 1; off < 64; off <<= 1) { float t2 = __shfl_up(cr, off); if (lane >= off) cr += t2; }
        float totr = __shfl(cr, 63);
        float wR = powf(10.f, (totr - cr) * rm) * rm;
        float rv = dvv * wR;
        #pragma unroll
        for (int off = 1; off < 64; off <<= 1) rv += __shfl_xor(rv, off);
        // op logits: sum_r rw[r]*hop[r][t] + opc_b[t]
        float4 hop = *reinterpret_cast<const float4*>(&lds[HOPB + (lane << 2)]);
        float p0 = rw * hop.x, p1 = rw * hop.y, p2 = rw * hop.z, p3 = rw * hop.w;
        #pragma unroll
        for (int off = 1; off < 64; off <<= 1) {
            p0 += __shfl_xor(p0, off); p1 += __shfl_xor(p1, off);
            p2 += __shfl_xor(p2, off); p3 += __shfl_xor(p3, off);
        }
        if (lane == 0) {
            float o0 = p0 + opc_b[0], o1 = p1 + opc_b[1];
            float o2v = p2 + opc_b[2], o3 = p3 + opc_b[3];
            int op = 0; float bm = o0;
            if (o1 > bm) { bm = o1; op = 1; }
            if (o2v > bm) { bm = o2v; op = 2; }
            if (o3 > bm) { bm = o3; op = 3; }
            float l = lv, r = rv, res, vl = 1.f;
            if (op == 0)      res = l + r;
            else if (op == 1) res = l - r;
            else if (op == 2) res = l * r;
            else { bool bad = fabsf(r) < 1e-6f; res = bad ? 0.f : (l / r); vl = bad ? 0.f : 1.f; }
            float rc = (res > 0.f) ? log1pf(res) : ((res < 0.f) ? -log1pf(-res) : 0.f);
            lds[M_DG + 0] = rc; lds[M_DG + 1] = vl;
            out[O_RES + b]   = res;
            out[O_VALID + b] = vl;
            out[O_LEFT + b]  = l;
            out[O_RIGHT + b] = r;
            out[O_OPL + (b << 2) + 0] = o0;
            out[O_OPL + (b << 2) + 1] = o1;
            out[O_OPL + (b << 2) + 2] = o2v;
            out[O_OPL + (b << 2) + 3] = o3;
        }
    }
    __syncthreads();
    if (tid < 64) {
        float rc = lds[M_DG + 0], vl = lds[M_DG + 1];
        out[O_REMB + (b << 6) + tid] = rc * res_w[tid] + vl * res_w[64 + tid] + res_b[tid];
        out[O_RW + (b << 6) + tid] = lds[M_SD + tid];
    }
}

extern "C" void kernel_launch(void* const* d_in, const int* in_sizes, int n_in,
                              void* d_out, int out_size, void* d_ws, size_t ws_size,
                              hipStream_t stream)
{
    fsa_kernel<<<dim3(BATCH), dim3(256), 0, stream>>>(
        (const int*)d_in[0],
        (const float*)d_in[1],  (const float*)d_in[2],  (const float*)d_in[3],
        (const float*)d_in[4],  (const float*)d_in[5],  (const float*)d_in[6],  (const float*)d_in[7],
        (const float*)d_in[8],  (const float*)d_in[9],  (const float*)d_in[10], (const float*)d_in[11],
        (const float*)d_in[12], (const float*)d_in[13], (const float*)d_in[14], (const float*)d_in[15],
        (const float*)d_in[16], (const float*)d_in[17], (const float*)d_in[18], (const float*)d_in[19],
        (const float*)d_in[20], (const float*)d_in[21], (const float*)d_in[22], (const float*)d_in[23],
        (const float*)d_in[24], (const float*)d_in[25], (const float*)d_in[26], (const float*)d_in[27],
        (float*)d_out);
}

// Round 14
// 1074.017 us; speedup vs baseline: 1.1988x; 1.1988x over previous
//
#include <hip/hip_runtime.h>
#include <math.h>

// B=4096, L=64, H=64, V=21, NH=4, HD=16, FF=128, NL=2
constexpr int BATCH = 4096;

typedef float v2f __attribute__((ext_vector_type(2)));
// packed fp32 FMA in plain C: compiler may form v_pk_fma_f32 (with SGPR weight
// operands / op_sel splat) or scalarize to two v_fma_f32 — both correct.
#define PKFMA(acc, a, w) (acc) = (a) * (w) + (acc)
__device__ __forceinline__ v2f dup2(float x) { v2f r; r[0] = x; r[1] = x; return r; }

// ---------------- LDS regions (float indices), total 39,168 B -> 4 blocks/CU
constexpr int A    = 0;
constexpr int B0   = 4352;
constexpr int PS   = B0 + 4096;     // 4x64 LN partial sums
constexpr int PSQ  = PS + 256;      // 4x64 LN partial sumsq
constexpr int HOPB = PS;            // head: hop[r][4] reuses dead PS region
constexpr int MB   = 9024;
constexpr int M_MASK = MB + 0;
constexpr int M_DVAL = MB + 64;
constexpr int M_ISD  = MB + 128;
constexpr int M_SD   = MB + 192;    // final rw
constexpr int M_DG   = MB + 320;    // scalars
constexpr int M_DVEC = MB + 384;    // g diagonal
constexpr int M_S    = MB + 448;    // prefix sums (log2 units)
constexpr int M_PRU  = MB + 512;    // prior g[i,i+1]
constexpr int M_PRD  = MB + 576;    // prior g[i,i]
constexpr int M_SU   = MB + 640;    // final scores
constexpr int LDSN   = MB + 768;    // 9792 floats = 39,168 B

// ---------------- output layout (floats) ----------------
constexpr int O_RES   = 0;
constexpr int O_REMB  = 4096;
constexpr int O_VALID = 266240;
constexpr int O_LEFT  = 270336;
constexpr int O_RIGHT = 274432;
constexpr int O_OPL   = 278528;
constexpr int O_RW    = 294912;

#define LN_PART() do {                                                    \
    float s_ = 0.f, q_ = 0.f;                                             \
    _Pragma("unroll") for (int j = 0; j < 16; ++j) {                      \
        s_ += xr[j]; q_ = fmaf(xr[j], xr[j], q_); }                       \
    lds[PS  + (wv << 6) + lane] = s_;                                     \
    lds[PSQ + (wv << 6) + lane] = q_;                                     \
} while (0)

#define LN_APPLY(GPTR, BPTR) do {                                         \
    float fs_ = lds[PS + lane] + lds[PS + 64 + lane]                      \
              + lds[PS + 128 + lane] + lds[PS + 192 + lane];              \
    float fq_ = lds[PSQ + lane] + lds[PSQ + 64 + lane]                    \
              + lds[PSQ + 128 + lane] + lds[PSQ + 192 + lane];            \
    float mu_ = fs_ * 0.015625f;                                          \
    float inv_ = rsqrtf(fq_ * 0.015625f - mu_ * mu_ + 1e-6f);             \
    _Pragma("unroll") for (int j = 0; j < 16; ++j) {                      \
        int c_ = c0 + j;                                                  \
        lds[A + c_ * 64 + lane] =                                         \
            (xr[j] - mu_) * inv_ * (GPTR)[c_] + (BPTR)[c_];               \
    }                                                                     \
} while (0)

__global__ void __launch_bounds__(256, 4) fsa_kernel(
    const int* __restrict__ tok,
    const float* __restrict__ emb, const float* __restrict__ np_w, const float* __restrict__ np_b,
    const float* __restrict__ grp_wq, const float* __restrict__ grp_bq,
    const float* __restrict__ grp_wk, const float* __restrict__ grp_bk,
    const float* __restrict__ grp_ln_g, const float* __restrict__ grp_ln_b,
    const float* __restrict__ attn_w, const float* __restrict__ attn_b,
    const float* __restrict__ ln1_g, const float* __restrict__ ln1_b,
    const float* __restrict__ ln2_g, const float* __restrict__ ln2_b,
    const float* __restrict__ ffn_w1, const float* __restrict__ ffn_b1,
    const float* __restrict__ ffn_w2, const float* __restrict__ ffn_b2,
    const float* __restrict__ enc_g, const float* __restrict__ enc_b,
    const float* __restrict__ red_w, const float* __restrict__ red_b,
    const float* __restrict__ opc_w, const float* __restrict__ opc_b,
    const float* __restrict__ res_w, const float* __restrict__ res_b,
    float* __restrict__ out)
{
    __shared__ __align__(16) float lds[LDSN];
    const int b = blockIdx.x;
    const int tid = threadIdx.x;
    const int lane = tid & 63;
    const int wv = __builtin_amdgcn_readfirstlane(tid >> 6);
    const int c0 = wv << 4;
    float xr[16];                 // x[lane][c0 .. c0+15] in registers

    // ================= embedding + positional encoding =================
    {
        int t = tok[(b << 6) + lane];
        float mk  = (t != 0) ? 1.f : 0.f;
        float isd = (t >= 4 && t <= 13) ? 1.f : 0.f;
        float dvv = ((float)t - 4.f) * isd;
        float iso = (t >= 14 && t <= 17) ? 1.f : 0.f;
        float opt = iso * ((float)t - 13.f);
        if (wv == 0) {
            lds[M_MASK + lane] = mk;  lds[M_DVAL + lane] = dvv; lds[M_ISD + lane] = isd;
            lds[M_PRU + lane] = 0.f;  lds[M_PRD + lane] = 0.f;
        }
        const float lg = -0.143911568f;   // -ln(10000)/64
        #pragma unroll
        for (int j = 0; j < 16; ++j) {
            int c = c0 + j;
            float freq = expf((float)(c & ~1) * lg);
            float ang = (float)lane * freq;
            float pe = (c & 1) ? cosf(ang) : sinf(ang);
            xr[j] = emb[t * 64 + c] * 8.f
                  + dvv * np_w[c] + isd * np_w[64 + c]
                  + opt * np_w[128 + c] + iso * np_w[192 + c]
                  + np_b[c] + pe;
        }
        LN_PART();                // partials for first gLN
    }
    __syncthreads();
    const unsigned long long mall = __ballot(lds[M_MASK + lane] > 0.f);

    // ================= transformer layers =================
    for (int il = 0; il < 2; ++il) {
        const float* gwq = grp_wq + il * 4096; const float* gbq = grp_bq + (il << 6);
        const float* gwk = grp_wk + il * 4096; const float* gbk = grp_bk + (il << 6);
        const float* glg = grp_ln_g + (il << 6); const float* glb = grp_ln_b + (il << 6);
        const float* aw  = attn_w + il * 16384;  const float* ab  = attn_b + (il << 8);
        const float* l1g = ln1_g + (il << 6);    const float* l1b = ln1_b + (il << 6);
        const float* l2g = ln2_g + (il << 6);    const float* l2b = ln2_b + (il << 6);
        const float* fw1 = ffn_w1 + il * 8192;   const float* fb1 = ffn_b1 + (il << 7);
        const float* fw2 = ffn_w2 + il * 8192;   const float* fb2 = ffn_b2 + (il << 6);

        // ---- group attention: fused gQ/gK GEMM + in-register adjacent dots ----
        LN_APPLY(glg, glb);               // h -> A (hT)
        __syncthreads();
        {
            v2f qa[8], ka[8];
            const v2f* gbq2 = reinterpret_cast<const v2f*>(gbq + c0);
            const v2f* gbk2 = reinterpret_cast<const v2f*>(gbk + c0);
            #pragma unroll
            for (int j = 0; j < 8; ++j) { qa[j] = gbq2[j]; ka[j] = gbk2[j]; }
            #pragma unroll 8
            for (int kk = 0; kk < 64; ++kk) {
                v2f a2 = dup2(lds[A + kk * 64 + lane]);
                const v2f* wq2 = reinterpret_cast<const v2f*>(gwq + kk * 64 + c0);
                const v2f* wk2 = reinterpret_cast<const v2f*>(gwk + kk * 64 + c0);
                #pragma unroll
                for (int j = 0; j < 8; ++j) {
                    PKFMA(qa[j], a2, wq2[j]);
                    PKFMA(ka[j], a2, wk2[j]);
                }
            }
            // adjacent-pair partial dots over this wave's 16-col slice
            v2f su2 = dup2(0.f), sd2 = dup2(0.f);
            #pragma unroll
            for (int j = 0; j < 8; ++j) {
                v2f kn, qn;
                kn[0] = __shfl_down(ka[j][0], 1); kn[1] = __shfl_down(ka[j][1], 1);
                qn[0] = __shfl_down(qa[j][0], 1); qn[1] = __shfl_down(qa[j][1], 1);
                PKFMA(su2, qa[j], kn);
                PKFMA(sd2, qn, ka[j]);
            }
            lds[B0 + (wv << 6) + lane] = su2[0] + su2[1];
            lds[B0 + 256 + (wv << 6) + lane] = sd2[0] + sd2[1];
            LN_PART();                              // LN1 partials (PS region)
        }
        __syncthreads();

        // scan (wave0); other waves idle one short phase
        if (wv == 0) {
            const int i = lane;
            float su = (lds[B0 + i] + lds[B0 + 64 + i]
                      + lds[B0 + 128 + i] + lds[B0 + 192 + i]) * 0.125f;
            float sdv = (lds[B0 + 256 + i] + lds[B0 + 320 + i]
                       + lds[B0 + 384 + i] + lds[B0 + 448 + i]) * 0.125f;
            float sd_im1 = __shfl_up(sdv, 1);     // s[i,i-1]
            float mi  = lds[M_MASK + i];
            float mup = (i < 63) ? lds[M_MASK + i + 1] : 0.f;
            float mdn = (i > 0)  ? lds[M_MASK + i - 1] : 0.f;
            float eu = (i < 63 && mi > 0.f && mup > 0.f) ? su : -1e9f;
            float ed = (i > 0 && mi > 0.f && mdn > 0.f) ? sd_im1 : -1e9f;
            float m = fmaxf(eu, ed);
            float nu, nd, ng;
            if (m <= -1e9f) { nu = 0.015625f; nd = 0.015625f; ng = 0.015625f; }
            else {
                float zu = __expf(eu - m), zd = __expf(ed - m);
                float iz = 1.f / (zu + zd);
                nu = zu * iz; nd = zd * iz; ng = 0.f;
            }
            float nd1 = __shfl_down(nd, 1);       // nb_dn of row i+1
            float pd = lds[M_PRD + i];
            float dsym = sqrtf(ng * ng + 1e-9f);
            float d2 = pd + (1.f - pd) * dsym;
            lds[M_DVEC + i] = d2; lds[M_PRD + i] = d2;
            float la2 = 0.f;                      // log2 units
            if (i < 63) {
                float pu = lds[M_PRU + i];
                float as_ = sqrtf(nu * nd1 + 1e-9f);
                float a2v = pu + (1.f - pu) * as_;
                la2 = __log2f(a2v + 1e-9f);
                lds[M_PRU + i] = exp2f(la2) + 1e-9f;   // next-layer prior
            }
            float x = __shfl_up(la2, 1);
            if (i == 0) x = 0.f;
            #pragma unroll
            for (int off = 1; off < 64; off <<= 1) {
                float t2 = __shfl_up(x, off);
                if (i >= off) x += t2;
            }
            lds[M_S + i] = x;                     // S2[i] = log2 prefix sums
        }
        __syncthreads();

        // ---- MHA: wave wv owns head wv; lane owns row=lane; JIT K/V tiles ----
        LN_APPLY(l1g, l1b);               // h -> A
        __syncthreads();
        {
            const int hb = wv << 4;
            const int TB = B0 + wv * 640;      // wave-local K(16x20) + V(16x20) tile
            const int jl = lane & 15, cq = lane >> 4;
            const float SCL = 0.36067376f;     // 0.25 * log2(e)
            v2f qa[8];
            const v2f* ab2 = reinterpret_cast<const v2f*>(ab + hb);
            #pragma unroll
            for (int j = 0; j < 8; ++j) qa[j] = ab2[j];
            #pragma unroll 8
            for (int kk = 0; kk < 64; ++kk) {
                v2f a2 = dup2(lds[A + kk * 64 + lane]);
                const v2f* wq2 = reinterpret_cast<const v2f*>(aw + kk * 64 + hb);
                #pragma unroll
                for (int j = 0; j < 8; ++j) PKFMA(qa[j], a2, wq2[j]);
            }
            const float Sr2 = lds[M_S + lane];
            const float dvr = lds[M_DVEC + lane];
            v2f o2[8];
            #pragma unroll
            for (int c = 0; c < 8; ++c) o2[c] = dup2(0.f);
            float mrun = -1e30f, z = 0.f;
            for (int jt = 0; jt < 4; ++jt) {
                {   // JIT K/V tile: rows jt*16+jl, cols hb+cq*4..+3 (wave-local)
                    v2f kacc[2], vacc[2];
                    const v2f* kb2 = reinterpret_cast<const v2f*>(ab + 64 + hb + (cq << 2));
                    const v2f* vb2 = reinterpret_cast<const v2f*>(ab + 128 + hb + (cq << 2));
                    kacc[0] = kb2[0]; kacc[1] = kb2[1];
                    vacc[0] = vb2[0]; vacc[1] = vb2[1];
                    const int row = (jt << 4) + jl;
                    #pragma unroll 8
                    for (int kk = 0; kk < 64; ++kk) {
                        v2f a2 = dup2(lds[A + kk * 64 + row]);
                        const v2f* wk2  = reinterpret_cast<const v2f*>(aw + 4096 + kk * 64 + hb + (cq << 2));
                        const v2f* wv2  = reinterpret_cast<const v2f*>(aw + 8192 + kk * 64 + hb + (cq << 2));
                        PKFMA(kacc[0], a2, wk2[0]); PKFMA(kacc[1], a2, wk2[1]);
                        PKFMA(vacc[0], a2, wv2[0]); PKFMA(vacc[1], a2, wv2[1]);
                    }
                    *reinterpret_cast<float4*>(&lds[TB + jl * 20 + (cq << 2)]) =
                        make_float4(kacc[0][0], kacc[0][1], kacc[1][0], kacc[1][1]);
                    *reinterpret_cast<float4*>(&lds[TB + 320 + jl * 20 + (cq << 2)]) =
                        make_float4(vacc[0][0], vacc[0][1], vacc[1][0], vacc[1][1]);
                    asm volatile("s_waitcnt lgkmcnt(0)" ::: "memory");  // wave-local fence
                }
                #pragma unroll
                for (int half = 0; half < 2; ++half) {
                    float sc[8]; float tm = -1e30f;
                    #pragma unroll
                    for (int jj = 0; jj < 8; ++jj) {
                        const int jloc = (half << 3) + jj;
                        const int j = (jt << 4) + jloc;
                        v2f s2 = dup2(0.f);
                        #pragma unroll
                        for (int c4 = 0; c4 < 4; ++c4) {
                            const float4 kv = *reinterpret_cast<const float4*>(
                                &lds[TB + jloc * 20 + (c4 << 2)]);
                            v2f klo; klo[0] = kv.x; klo[1] = kv.y;
                            v2f khi; khi[0] = kv.z; khi[1] = kv.w;
                            PKFMA(s2, qa[(c4 << 1)], klo);
                            PKFMA(s2, qa[(c4 << 1) + 1], khi);
                        }
                        float s = s2[0] + s2[1];
                        s = ((mall >> j) & 1ull) ? s * SCL : -1e9f;
                        sc[jj] = s; tm = fmaxf(tm, s);
                    }
                    float mn = fmaxf(mrun, tm);
                    float rs = exp2f(mrun - mn);
                    z *= rs;
                    v2f rs2 = dup2(rs);
                    #pragma unroll
                    for (int c = 0; c < 8; ++c) o2[c] *= rs2;
                    mrun = mn;
                    #pragma unroll
                    for (int jj = 0; jj < 8; ++jj) {
                        const int jloc = (half << 3) + jj;
                        const int j = (jt << 4) + jloc;
                        float e = exp2f(sc[jj] - mn);
                        z += e;
                        float Sj2 = lds[M_S + j];
                        float g = (j == lane) ? dvr
                                  : (exp2f((j > lane) ? (Sj2 - Sr2) : (Sr2 - Sj2)) + 1e-9f);
                        v2f w2 = dup2(e * g);
                        #pragma unroll
                        for (int c4 = 0; c4 < 4; ++c4) {
                            const float4 vv = *reinterpret_cast<const float4*>(
                                &lds[TB + 320 + jloc * 20 + (c4 << 2)]);
                            v2f vlo; vlo[0] = vv.x; vlo[1] = vv.y;
                            v2f vhi; vhi[0] = vv.z; vhi[1] = vv.w;
                            PKFMA(o2[(c4 << 1)], w2, vlo);
                            PKFMA(o2[(c4 << 1) + 1], w2, vhi);
                        }
                    }
                }
            }
            float iz = 1.f / z;
            __syncthreads();          // all waves' h reads done before O overwrites A
            #pragma unroll
            for (int c = 0; c < 8; ++c) {
                lds[A + lane * 65 + hb + (c << 1)]     = o2[c][0] * iz;
                lds[A + lane * 65 + hb + (c << 1) + 1] = o2[c][1] * iz;
            }
            __syncthreads();
            // O-proj: xr += O @ Wo + bo; then LN2 partials (same phase)
            const float* Wo = aw + 12288; const float* bo = ab + 192;
            v2f acc[8];
            const v2f* bo2 = reinterpret_cast<const v2f*>(bo + c0);
            #pragma unroll
            for (int j = 0; j < 8; ++j) acc[j] = bo2[j];
            #pragma unroll 8
            for (int dd = 0; dd < 64; ++dd) {
                v2f a2 = dup2(lds[A + lane * 65 + dd]);
                const v2f* wr2 = reinterpret_cast<const v2f*>(Wo + dd * 64 + c0);
                #pragma unroll
                for (int j = 0; j < 8; ++j) PKFMA(acc[j], a2, wr2[j]);
            }
            #pragma unroll
            for (int j = 0; j < 8; ++j) {
                xr[(j << 1)]     += acc[j][0];
                xr[(j << 1) + 1] += acc[j][1];
            }
            LN_PART();
        }
        __syncthreads();

        // ---- FFN (two 64-col halves of F share one buffer in B0) ----
        LN_APPLY(l2g, l2b);               // h -> A (overwrites O)
        __syncthreads();
        {   // F-lo
            v2f fa[8];
            const v2f* fb2v = reinterpret_cast<const v2f*>(fb1 + c0);
            #pragma unroll
            for (int j = 0; j < 8; ++j) fa[j] = fb2v[j];
            #pragma unroll 8
            for (int kk = 0; kk < 64; ++kk) {
                v2f a2 = dup2(lds[A + kk * 64 + lane]);
                const v2f* wr2 = reinterpret_cast<const v2f*>(fw1 + kk * 128 + c0);
                #pragma unroll
                for (int j = 0; j < 8; ++j) PKFMA(fa[j], a2, wr2[j]);
            }
            #pragma unroll
            for (int j = 0; j < 8; ++j) {
                lds[B0 + (c0 + (j << 1)) * 64 + lane]     = fmaxf(fa[j][0], 0.f);
                lds[B0 + (c0 + (j << 1) + 1) * 64 + lane] = fmaxf(fa[j][1], 0.f);
            }
        }
        __syncthreads();
        {   // xr += F-lo @ W2[0:64]
            v2f acc[8];
            const v2f* fb2v = reinterpret_cast<const v2f*>(fb2 + c0);
            #pragma unroll
            for (int j = 0; j < 8; ++j) acc[j] = fb2v[j];
            #pragma unroll 8
            for (int kk = 0; kk < 64; ++kk) {
                v2f a2 = dup2(lds[B0 + kk * 64 + lane]);
                const v2f* wr2 = reinterpret_cast<const v2f*>(fw2 + kk * 64 + c0);
                #pragma unroll
                for (int j = 0; j < 8; ++j) PKFMA(acc[j], a2, wr2[j]);
            }
            #pragma unroll
            for (int j = 0; j < 8; ++j) {
                xr[(j << 1)]     += acc[j][0];
                xr[(j << 1) + 1] += acc[j][1];
            }
        }
        __syncthreads();
        {   // F-hi
            v2f fa[8];
            const v2f* fb2v = reinterpret_cast<const v2f*>(fb1 + 64 + c0);
            #pragma unroll
            for (int j = 0; j < 8; ++j) fa[j] = fb2v[j];
            #pragma unroll 8
            for (int kk = 0; kk < 64; ++kk) {
                v2f a2 = dup2(lds[A + kk * 64 + lane]);
                const v2f* wr2 = reinterpret_cast<const v2f*>(fw1 + kk * 128 + 64 + c0);
                #pragma unroll
                for (int j = 0; j < 8; ++j) PKFMA(fa[j], a2, wr2[j]);
            }
            #pragma unroll
            for (int j = 0; j < 8; ++j) {
                lds[B0 + (c0 + (j << 1)) * 64 + lane]     = fmaxf(fa[j][0], 0.f);
                lds[B0 + (c0 + (j << 1) + 1) * 64 + lane] = fmaxf(fa[j][1], 0.f);
            }
        }
        __syncthreads();
        {   // xr += F-hi @ W2[64:128]; then next-LN partials (same phase)
            v2f acc[8];
            #pragma unroll
            for (int j = 0; j < 8; ++j) acc[j] = dup2(0.f);
            #pragma unroll 8
            for (int kk = 0; kk < 64; ++kk) {
                v2f a2 = dup2(lds[B0 + kk * 64 + lane]);
                const v2f* wr2 = reinterpret_cast<const v2f*>(fw2 + (64 + kk) * 64 + c0);
                #pragma unroll
                for (int j = 0; j < 8; ++j) PKFMA(acc[j], a2, wr2[j]);
            }
            #pragma unroll
            for (int j = 0; j < 8; ++j) {
                xr[(j << 1)]     += acc[j][0];
                xr[(j << 1) + 1] += acc[j][1];
            }
            LN_PART();                    // for next gLN (or enc LN after last layer)
        }
        __syncthreads();
    }

    // ================= reduction / calculator head =================
    LN_APPLY(enc_g, enc_b);   // final h -> A (hT)
    __syncthreads();
    if (tid < 64) {           // scores + op-logit row dots (shared h reads)
        float s = 0.f, h0 = 0.f, h1 = 0.f, h2 = 0.f, h3 = 0.f;
        #pragma unroll 8
        for (int c2 = 0; c2 < 64; ++c2) {
            float hv = lds[A + c2 * 64 + tid];
            s  = fmaf(hv, red_w[c2], s);
            h0 = fmaf(hv, opc_w[(c2 << 2) + 0], h0);
            h1 = fmaf(hv, opc_w[(c2 << 2) + 1], h1);
            h2 = fmaf(hv, opc_w[(c2 << 2) + 2], h2);
            h3 = fmaf(hv, opc_w[(c2 << 2) + 3], h3);
        }
        s += red_b[0];
        s += (1.f - lds[M_MASK + tid]) * -1e9f;
        lds[M_SU + tid] = s;
        *reinterpret_cast<float4*>(&lds[HOPB + (tid << 2)]) = make_float4(h0, h1, h2, h3);
    }
    __syncthreads();

    if (wv == 0) {        // softmax, scans, digits, op select, scalar outs
        float s = lds[M_SU + lane];
        float m = s;
        #pragma unroll
        for (int off = 1; off < 64; off <<= 1) m = fmaxf(m, __shfl_xor(m, off));
        float ee = expf(s - m);
        float z = ee;
        #pragma unroll
        for (int off = 1; off < 64; off <<= 1) z += __shfl_xor(z, off);
        float rw = ee / z;
        lds[M_SD + lane] = rw;
        float cum = rw;
        #pragma unroll
        for (int off = 1; off < 64; off <<= 1) { float t2 = __shfl_up(cum, off); if (lane >= off) cum += t2; }
        float isd = lds[M_ISD + lane], dvv = lds[M_DVAL + lane];
        float lm = (1.f - cum) * isd;
        float rm = (cum - rw) * isd;
        float cl = lm;
        #pragma unroll
        for (int off = 1; off < 64; off <<= 1) { float t2 = __shfl_up(cl, off); if (lane >= off) cl += t2; }
        float totl = __shfl(cl, 63);
        float wL = powf(10.f, (totl - cl) * lm) * lm;
        float lv = dvv * wL;
        #pragma unroll
        for (int off = 1; off < 64; off <<= 1) lv += __shfl_xor(lv, off);
        float cr = rm;
        #pragma unroll
        for (int off = 1; off < 64; off <<= 1) { float t2 = __shfl_up(cr, off); if (lane >= off) cr += t2; }
        float totr = __shfl(cr, 63);
        float wR = powf(10.f, (totr - cr) * rm) * rm;
        float rv = dvv * wR;
        #pragma unroll
        for (int off = 1; off < 64; off <<= 1) rv += __shfl_xor(rv, off);
        // op logits: sum_r rw[r]*hop[r][t] + opc_b[t]
        float4 hop = *reinterpret_cast<const float4*>(&lds[HOPB + (lane << 2)]);
        float p0 = rw * hop.x, p1 = rw * hop.y, p2 = rw * hop.z, p3 = rw * hop.w;
        #pragma unroll
        for (int off = 1; off < 64; off <<= 1) {
            p0 += __shfl_xor(p0, off); p1 += __shfl_xor(p1, off);
            p2 += __shfl_xor(p2, off); p3 += __shfl_xor(p3, off);
        }
        if (lane == 0) {
            float o0 = p0 + opc_b[0], o1 = p1 + opc_b[1];
            float o2v = p2 + opc_b[2], o3 = p3 + opc_b[3];
            int op = 0; float bm = o0;
            if (o1 > bm) { bm = o1; op = 1; }
            if (o2v > bm) { bm = o2v; op = 2; }
            if (o3 > bm) { bm = o3; op = 3; }
            float l = lv, r = rv, res, vl = 1.f;
            if (op == 0)      res = l + r;
            else if (op == 1) res = l - r;
            else if (op == 2) res = l * r;
            else { bool bad = fabsf(r) < 1e-6f; res = bad ? 0.f : (l / r); vl = bad ? 0.f : 1.f; }
            float rc = (res > 0.f) ? log1pf(res) : ((res < 0.f) ? -log1pf(-res) : 0.f);
            lds[M_DG + 0] = rc; lds[M_DG + 1] = vl;
            out[O_RES + b]   = res;
            out[O_VALID + b] = vl;
            out[O_LEFT + b]  = l;
            out[O_RIGHT + b] = r;
            out[O_OPL + (b << 2) + 0] = o0;
            out[O_OPL + (b << 2) + 1] = o1;
            out[O_OPL + (b << 2) + 2] = o2v;
            out[O_OPL + (b << 2) + 3] = o3;
        }
    }
    __syncthreads();
    if (tid < 64) {
        float rc = lds[M_DG + 0], vl = lds[M_DG + 1];
        out[O_REMB + (b << 6) + tid] = rc * res_w[tid] + vl * res_w[64 + tid] + res_b[tid];
        out[O_RW + (b << 6) + tid] = lds[M_SD + tid];
    }
}

extern "C" void kernel_launch(void* const* d_in, const int* in_sizes, int n_in,
                              void* d_out, int out_size, void* d_ws, size_t ws_size,
                              hipStream_t stream)
{
    fsa_kernel<<<dim3(BATCH), dim3(256), 0, stream>>>(
        (const int*)d_in[0],
        (const float*)d_in[1],  (const float*)d_in[2],  (const float*)d_in[3],
        (const float*)d_in[4],  (const float*)d_in[5],  (const float*)d_in[6],  (const float*)d_in[7],
        (const float*)d_in[8],  (const float*)d_in[9],  (const float*)d_in[10], (const float*)d_in[11],
        (const float*)d_in[12], (const float*)d_in[13], (const float*)d_in[14], (const float*)d_in[15],
        (const float*)d_in[16], (const float*)d_in[17], (const float*)d_in[18], (const float*)d_in[19],
        (const float*)d_in[20], (const float*)d_in[21], (const float*)d_in[22], (const float*)d_in[23],
        (const float*)d_in[24], (const float*)d_in[25], (const float*)d_in[26], (const float*)d_in[27],
        (float*)d_out);
}

// Round 15
// 951.836 us; speedup vs baseline: 1.3527x; 1.1284x over previous
//
#include <hip/hip_runtime.h>
#include <math.h>

// B=4096, L=64, H=64, V=21, NH=4, HD=16, FF=128, NL=2
constexpr int BATCH = 4096;

// ---------------- LDS regions (float indices), total 39,168 B -> 4 blocks/CU
// A  [0,4352):      hT [c][r] stride 64 / gK^T s64 / O rows s65
// B0 [4352,9024):   PS/PSQ (512) | gQ^T s64 / F s64 (4096) | per-wave KV tiles
//                   (wv*640: K 16x20, V 16x20) | final hR at B0+512 stride 65
// M  [9024,9792):   masks, scan state
constexpr int A    = 0;
constexpr int B0   = 4352;
constexpr int PS   = B0;            // 4x64 LN partial sums
constexpr int PSQ  = B0 + 256;      // 4x64 LN partial sumsq
constexpr int BH   = B0 + 512;      // final hR, 64x65
constexpr int MB   = 9024;
constexpr int M_MASK = MB + 0;
constexpr int M_DVAL = MB + 64;
constexpr int M_ISD  = MB + 128;
constexpr int M_SD   = MB + 192;    // final rw
constexpr int M_NBU  = MB + 256;    // pooled
constexpr int M_DG   = MB + 320;    // scalars
constexpr int M_DVEC = MB + 384;    // g diagonal
constexpr int M_S    = MB + 448;    // prefix sums
constexpr int M_PRU  = MB + 512;    // prior g[i,i+1]
constexpr int M_PRD  = MB + 576;    // prior g[i,i]
constexpr int M_SU   = MB + 640;    // s_up
constexpr int M_SDN  = MB + 704;    // s_dn
constexpr int LDSN   = MB + 768;    // 9792 floats = 39,168 B

// ---------------- output layout (floats) ----------------
constexpr int O_RES   = 0;
constexpr int O_REMB  = 4096;
constexpr int O_VALID = 266240;
constexpr int O_LEFT  = 270336;
constexpr int O_RIGHT = 274432;
constexpr int O_OPL   = 278528;
constexpr int O_RW    = 294912;

// LN of xr; stats via 4-wave LDS partial reduce; then STORE per column.
#define LN_STORE(GPTR, BPTR, STORE) do {                                  \
    float s_ = 0.f, q_ = 0.f;                                             \
    _Pragma("unroll") for (int j = 0; j < 16; ++j) {                      \
        s_ += xr[j]; q_ = fmaf(xr[j], xr[j], q_); }                       \
    lds[PS  + (wv << 6) + lane] = s_;                                     \
    lds[PSQ + (wv << 6) + lane] = q_;                                     \
    __syncthreads();                                                      \
    float fs_ = lds[PS + lane] + lds[PS + 64 + lane]                      \
              + lds[PS + 128 + lane] + lds[PS + 192 + lane];              \
    float fq_ = lds[PSQ + lane] + lds[PSQ + 64 + lane]                    \
              + lds[PSQ + 128 + lane] + lds[PSQ + 192 + lane];            \
    float mu_ = fs_ * 0.015625f;                                          \
    float inv_ = rsqrtf(fq_ * 0.015625f - mu_ * mu_ + 1e-6f);             \
    _Pragma("unroll") for (int j = 0; j < 16; ++j) {                      \
        int c_ = c0 + j;                                                  \
        float hv_ = (xr[j] - mu_) * inv_ * (GPTR)[c_] + (BPTR)[c_];       \
        STORE;                                                            \
    }                                                                     \
    __syncthreads();                                                      \
} while (0)

__global__ void __launch_bounds__(256, 4) fsa_kernel(
    const int* __restrict__ tok,
    const float* __restrict__ emb, const float* __restrict__ np_w, const float* __restrict__ np_b,
    const float* __restrict__ grp_wq, const float* __restrict__ grp_bq,
    const float* __restrict__ grp_wk, const float* __restrict__ grp_bk,
    const float* __restrict__ grp_ln_g, const float* __restrict__ grp_ln_b,
    const float* __restrict__ attn_w, const float* __restrict__ attn_b,
    const float* __restrict__ ln1_g, const float* __restrict__ ln1_b,
    const float* __restrict__ ln2_g, const float* __restrict__ ln2_b,
    const float* __restrict__ ffn_w1, const float* __restrict__ ffn_b1,
    const float* __restrict__ ffn_w2, const float* __restrict__ ffn_b2,
    const float* __restrict__ enc_g, const float* __restrict__ enc_b,
    const float* __restrict__ red_w, const float* __restrict__ red_b,
    const float* __restrict__ opc_w, const float* __restrict__ opc_b,
    const float* __restrict__ res_w, const float* __restrict__ res_b,
    float* __restrict__ out)
{
    __shared__ __align__(16) float lds[LDSN];
    const int b = blockIdx.x;
    const int tid = threadIdx.x;
    const int lane = tid & 63;
    const int wv = __builtin_amdgcn_readfirstlane(tid >> 6);
    const int c0 = wv << 4;
    float xr[16];                 // x[lane][c0 .. c0+15] in registers

    // ================= embedding + positional encoding =================
    {
        int t = tok[(b << 6) + lane];
        float mk  = (t != 0) ? 1.f : 0.f;
        float isd = (t >= 4 && t <= 13) ? 1.f : 0.f;
        float dvv = ((float)t - 4.f) * isd;
        float iso = (t >= 14 && t <= 17) ? 1.f : 0.f;
        float opt = iso * ((float)t - 13.f);
        if (wv == 0) {
            lds[M_MASK + lane] = mk;  lds[M_DVAL + lane] = dvv; lds[M_ISD + lane] = isd;
            lds[M_PRU + lane] = 0.f;  lds[M_PRD + lane] = 0.f;
        }
        const float lg = -0.143911568f;   // -ln(10000)/64
        #pragma unroll
        for (int j = 0; j < 16; ++j) {
            int c = c0 + j;
            float freq = expf((float)(c & ~1) * lg);
            float ang = (float)lane * freq;
            float pe = (c & 1) ? cosf(ang) : sinf(ang);
            xr[j] = emb[t * 64 + c] * 8.f
                  + dvv * np_w[c] + isd * np_w[64 + c]
                  + opt * np_w[128 + c] + iso * np_w[192 + c]
                  + np_b[c] + pe;
        }
    }
    __syncthreads();
    // 64-bit pairmask register (bit j = mask[j] > 0), wave-uniform (SGPRs)
    const unsigned long long mall = __ballot(lds[M_MASK + lane] > 0.f);

    // ================= transformer layers =================
    for (int il = 0; il < 2; ++il) {
        const float* gwq = grp_wq + il * 4096; const float* gbq = grp_bq + (il << 6);
        const float* gwk = grp_wk + il * 4096; const float* gbk = grp_bk + (il << 6);
        const float* glg = grp_ln_g + (il << 6); const float* glb = grp_ln_b + (il << 6);
        const float* aw  = attn_w + il * 16384;  const float* ab  = attn_b + (il << 8);
        const float* l1g = ln1_g + (il << 6);    const float* l1b = ln1_b + (il << 6);
        const float* l2g = ln2_g + (il << 6);    const float* l2b = ln2_b + (il << 6);
        const float* fw1 = ffn_w1 + il * 8192;   const float* fb1 = ffn_b1 + (il << 7);
        const float* fw2 = ffn_w2 + il * 8192;   const float* fb2 = ffn_b2 + (il << 6);

        // ---- group (constituent) attention ----
        LN_STORE(glg, glb, lds[A + c_ * 64 + lane] = hv_);
        {   // fused gQ/gK GEMM streaming hT
            float qa[16], ka[16];
            #pragma unroll
            for (int j = 0; j < 16; ++j) { qa[j] = gbq[c0 + j]; ka[j] = gbk[c0 + j]; }
            #pragma unroll 8
            for (int kk = 0; kk < 64; ++kk) {
                float a = lds[A + kk * 64 + lane];
                const float* wq = gwq + kk * 64 + c0;
                const float* wk = gwk + kk * 64 + c0;
                #pragma unroll
                for (int j = 0; j < 16; ++j) {
                    qa[j] = fmaf(a, wq[j], qa[j]);
                    ka[j] = fmaf(a, wk[j], ka[j]);
                }
            }
            #pragma unroll
            for (int j = 0; j < 16; ++j) lds[B0 + (c0 + j) * 64 + lane] = qa[j]; // gQ^T
            __syncthreads();          // hT reads done; gQ^T visible
            #pragma unroll
            for (int j = 0; j < 16; ++j) lds[A + (c0 + j) * 64 + lane] = ka[j];  // gK^T
            __syncthreads();
        }

        if (tid < 126) {              // s[i,i+1] and s[i+1,i]
            int i = tid >> 1, w = tid & 1;
            int ra = w ? i + 1 : i, rb = w ? i : i + 1;
            float s = 0.f;
            #pragma unroll 8
            for (int c2 = 0; c2 < 64; ++c2)
                s = fmaf(lds[B0 + c2 * 64 + ra], lds[A + c2 * 64 + rb], s);
            lds[(w ? M_SDN : M_SU) + i] = s * 0.125f;   // / sqrt(H)
        }
        __syncthreads();

        if (wv == 0) {   // merged: masked softmax + symmetrize + prior + shfl scan
            const int i = lane;
            float mi  = lds[M_MASK + i];
            float mup = (i < 63) ? lds[M_MASK + i + 1] : 0.f;
            float mdn = (i > 0)  ? lds[M_MASK + i - 1] : 0.f;
            float eu = (mi > 0.f && mup > 0.f) ? lds[M_SU + i] : -1e9f;
            float ed = (i > 0 && mi > 0.f && mdn > 0.f) ? lds[M_SDN + i - 1] : -1e9f;
            float m = fmaxf(eu, ed);
            float nu, nd, ng;
            if (m <= -1e9f) { nu = 0.015625f; nd = 0.015625f; ng = 0.015625f; }
            else {
                float zu = __expf(eu - m), zd = __expf(ed - m);
                float iz = 1.f / (zu + zd);
                nu = zu * iz; nd = zd * iz; ng = 0.f;
            }
            float nd1 = __shfl_down(nd, 1);       // nb_dn of row i+1
            float pd = lds[M_PRD + i];
            float dsym = sqrtf(ng * ng + 1e-9f);
            float d2 = pd + (1.f - pd) * dsym;
            lds[M_DVEC + i] = d2; lds[M_PRD + i] = d2;
            float la = 0.f;
            if (i < 63) {
                float pu = lds[M_PRU + i];
                float as_ = sqrtf(nu * nd1 + 1e-9f);
                float a2 = pu + (1.f - pu) * as_;
                la = logf(a2 + 1e-9f);
                lds[M_PRU + i] = __expf(la) + 1e-9f;   // next-layer prior
            }
            float x = __shfl_up(la, 1);
            if (i == 0) x = 0.f;
            #pragma unroll
            for (int off = 1; off < 64; off <<= 1) {
                float t2 = __shfl_up(x, off);
                if (i >= off) x += t2;
            }
            lds[M_S + i] = x;                     // S[i] = sum_{k<i} la[k]
        }
        __syncthreads();

        // ---- MHA: wave wv owns head wv; lane owns row=lane; JIT K/V tiles ----
        LN_STORE(l1g, l1b, lds[A + c_ * 64 + lane] = hv_);
        {
            const int hb = wv << 4;
            const int TB = B0 + wv * 640;      // wave-local K(16x20) + V(16x20) tile
            const int jl = lane & 15, cq = lane >> 4;
            // Q row for this lane (per-head 16 cols)
            float qa[16];
            #pragma unroll
            for (int j = 0; j < 16; ++j) qa[j] = ab[hb + j];
            #pragma unroll 8
            for (int kk = 0; kk < 64; ++kk) {
                float a = lds[A + kk * 64 + lane];
                const float* wq = aw + kk * 64 + hb;
                #pragma unroll
                for (int j = 0; j < 16; ++j) qa[j] = fmaf(a, wq[j], qa[j]);
            }
            float o[16];
            #pragma unroll
            for (int c = 0; c < 16; ++c) o[c] = 0.f;
            float mrun = -1e30f, z = 0.f;
            for (int jt = 0; jt < 4; ++jt) {
                {   // JIT K/V tile: rows jt*16+jl, cols hb+cq*4..+3 (wave-local)
                    float kacc[4], vacc[4];
                    #pragma unroll
                    for (int j = 0; j < 4; ++j) {
                        kacc[j] = ab[64 + hb + (cq << 2) + j];
                        vacc[j] = ab[128 + hb + (cq << 2) + j];
                    }
                    const int row = (jt << 4) + jl;
                    #pragma unroll 8
                    for (int kk = 0; kk < 64; ++kk) {
                        float a = lds[A + kk * 64 + row];
                        const float* wk  = aw + 4096 + kk * 64 + hb + (cq << 2);
                        const float* wvp = aw + 8192 + kk * 64 + hb + (cq << 2);
                        #pragma unroll
                        for (int j = 0; j < 4; ++j) {
                            kacc[j] = fmaf(a, wk[j], kacc[j]);
                            vacc[j] = fmaf(a, wvp[j], vacc[j]);
                        }
                    }
                    *reinterpret_cast<float4*>(&lds[TB + jl * 20 + (cq << 2)]) =
                        make_float4(kacc[0], kacc[1], kacc[2], kacc[3]);
                    *reinterpret_cast<float4*>(&lds[TB + 320 + jl * 20 + (cq << 2)]) =
                        make_float4(vacc[0], vacc[1], vacc[2], vacc[3]);
                    asm volatile("s_waitcnt lgkmcnt(0)" ::: "memory");  // wave-local fence
                }
                #pragma unroll
                for (int half = 0; half < 2; ++half) {
                    float sc[8]; float tm = -1e30f;
                    #pragma unroll
                    for (int jj = 0; jj < 8; ++jj) {
                        const int jloc = (half << 3) + jj;
                        const int j = (jt << 4) + jloc;
                        float s = 0.f;
                        #pragma unroll
                        for (int c4 = 0; c4 < 4; ++c4) {
                            const float4 kv = *reinterpret_cast<const float4*>(
                                &lds[TB + jloc * 20 + (c4 << 2)]);
                            s = fmaf(qa[(c4<<2)+0], kv.x, s); s = fmaf(qa[(c4<<2)+1], kv.y, s);
                            s = fmaf(qa[(c4<<2)+2], kv.z, s); s = fmaf(qa[(c4<<2)+3], kv.w, s);
                        }
                        s = ((mall >> j) & 1ull) ? s * 0.25f : -1e9f;
                        sc[jj] = s; tm = fmaxf(tm, s);
                    }
                    float mn = fmaxf(mrun, tm);
                    float rs = __expf(mrun - mn);
                    z *= rs;
                    #pragma unroll
                    for (int c = 0; c < 16; ++c) o[c] *= rs;
                    mrun = mn;
                    float Sr  = lds[M_S + lane];
                    float dvr = lds[M_DVEC + lane];
                    #pragma unroll
                    for (int jj = 0; jj < 8; ++jj) {
                        const int jloc = (half << 3) + jj;
                        const int j = (jt << 4) + jloc;
                        float e = __expf(sc[jj] - mn);
                        z += e;
                        float Sj = lds[M_S + j];
                        float g = (j == lane) ? dvr
                                  : (__expf((j > lane) ? (Sj - Sr) : (Sr - Sj)) + 1e-9f);
                        float w = e * g;
                        #pragma unroll
                        for (int c4 = 0; c4 < 4; ++c4) {
                            const float4 vv = *reinterpret_cast<const float4*>(
                                &lds[TB + 320 + jloc * 20 + (c4 << 2)]);
                            o[(c4<<2)+0] = fmaf(w, vv.x, o[(c4<<2)+0]);
                            o[(c4<<2)+1] = fmaf(w, vv.y, o[(c4<<2)+1]);
                            o[(c4<<2)+2] = fmaf(w, vv.z, o[(c4<<2)+2]);
                            o[(c4<<2)+3] = fmaf(w, vv.w, o[(c4<<2)+3]);
                        }
                    }
                }
            }
            float iz = 1.f / z;
            __syncthreads();          // all waves' h reads done before O overwrites A
            #pragma unroll
            for (int c = 0; c < 16; ++c) lds[A + lane * 65 + hb + c] = o[c] * iz;
            __syncthreads();
            // O-proj: xr += O @ Wo + bo (O rows stride 65, 2-way free)
            const float* Wo = aw + 12288; const float* bo = ab + 192;
            float acc[16];
            #pragma unroll
            for (int j = 0; j < 16; ++j) acc[j] = bo[c0 + j];
            #pragma unroll 8
            for (int dd = 0; dd < 64; ++dd) {
                float a = lds[A + lane * 65 + dd];
                const float* wr = Wo + dd * 64 + c0;
                #pragma unroll
                for (int j = 0; j < 16; ++j) acc[j] = fmaf(a, wr[j], acc[j]);
            }
            #pragma unroll
            for (int j = 0; j < 16; ++j) xr[j] += acc[j];
        }
        __syncthreads();              // O reads done before FFN LN overwrites A

        // ---- FFN (two 64-col halves of F share one buffer in B0) ----
        LN_STORE(l2g, l2b, lds[A + c_ * 64 + lane] = hv_);
        {   // F-lo
            float fa[16];
            #pragma unroll
            for (int j = 0; j < 16; ++j) fa[j] = fb1[c0 + j];
            #pragma unroll 8
            for (int kk = 0; kk < 64; ++kk) {
                float a = lds[A + kk * 64 + lane];
                const float* wr = fw1 + kk * 128 + c0;
                #pragma unroll
                for (int j = 0; j < 16; ++j) fa[j] = fmaf(a, wr[j], fa[j]);
            }
            #pragma unroll
            for (int j = 0; j < 16; ++j) lds[B0 + (c0 + j) * 64 + lane] = fmaxf(fa[j], 0.f);
        }
        __syncthreads();
        {   // xr += F-lo @ W2[0:64]
            float acc[16];
            #pragma unroll
            for (int j = 0; j < 16; ++j) acc[j] = fb2[c0 + j];
            #pragma unroll 8
            for (int kk = 0; kk < 64; ++kk) {
                float a = lds[B0 + kk * 64 + lane];
                const float* wr = fw2 + kk * 64 + c0;
                #pragma unroll
                for (int j = 0; j < 16; ++j) acc[j] = fmaf(a, wr[j], acc[j]);
            }
            #pragma unroll
            for (int j = 0; j < 16; ++j) xr[j] += acc[j];
        }
        __syncthreads();
        {   // F-hi
            float fa[16];
            #pragma unroll
            for (int j = 0; j < 16; ++j) fa[j] = fb1[64 + c0 + j];
            #pragma unroll 8
            for (int kk = 0; kk < 64; ++kk) {
                float a = lds[A + kk * 64 + lane];
                const float* wr = fw1 + kk * 128 + 64 + c0;
                #pragma unroll
                for (int j = 0; j < 16; ++j) fa[j] = fmaf(a, wr[j], fa[j]);
            }
            #pragma unroll
            for (int j = 0; j < 16; ++j) lds[B0 + (c0 + j) * 64 + lane] = fmaxf(fa[j], 0.f);
        }
        __syncthreads();
        {   // xr += F-hi @ W2[64:128]
            float acc[16];
            #pragma unroll
            for (int j = 0; j < 16; ++j) acc[j] = 0.f;
            #pragma unroll 8
            for (int kk = 0; kk < 64; ++kk) {
                float a = lds[B0 + kk * 64 + lane];
                const float* wr = fw2 + (64 + kk) * 64 + c0;
                #pragma unroll
                for (int j = 0; j < 16; ++j) acc[j] = fmaf(a, wr[j], acc[j]);
            }
            #pragma unroll
            for (int j = 0; j < 16; ++j) xr[j] += acc[j];
        }
        __syncthreads();   // B0 (F) reads done before next LN writes PS into B0
    }

    // ================= reduction / calculator head =================
    LN_STORE(enc_g, enc_b, lds[BH + lane * 65 + c_] = hv_);   // hR stride 65 at B0+512
    if (tid < 64) {       // scores = h @ red_w + red_b + (1-mask)*-1e9
        float s = 0.f;
        #pragma unroll 8
        for (int c2 = 0; c2 < 64; ++c2)
            s = fmaf(lds[BH + tid * 65 + c2], red_w[c2], s);
        s += red_b[0];
        s += (1.f - lds[M_MASK + tid]) * -1e9f;
        lds[M_SU + tid] = s;
    }
    __syncthreads();

    if (wv == 0) {        // softmax, scans, digit assembly (wave 0)
        float s = lds[M_SU + lane];
        float m = s;
        #pragma unroll
        for (int off = 1; off < 64; off <<= 1) m = fmaxf(m, __shfl_xor(m, off));
        float ee = expf(s - m);
        float z = ee;
        #pragma unroll
        for (int off = 1; off < 64; off <<= 1) z += __shfl_xor(z, off);
        float rw = ee / z;
        lds[M_SD + lane] = rw;
        float cum = rw;
        #pragma unroll
        for (int off = 1; off < 64; off <<= 1) { float t2 = __shfl_up(cum, off); if (lane >= off) cum += t2; }
        float isd = lds[M_ISD + lane], dvv = lds[M_DVAL + lane];
        float lm = (1.f - cum) * isd;
        float rm = (cum - rw) * isd;
        float cl = lm;
        #pragma unroll
        for (int off = 1; off < 64; off <<= 1) { float t2 = __shfl_up(cl, off); if (lane >= off) cl += t2; }
        float totl = __shfl(cl, 63);
        float wL = powf(10.f, (totl - cl) * lm) * lm;
        float lv = dvv * wL;
        #pragma unroll
        for (int off = 1; off < 64; off <<= 1) lv += __shfl_xor(lv, off);
        float cr = rm;
        #pragma unroll
        for (int off = 1; off < 64; off <<= 1) { float t2 = __shfl_up(cr, off); if (lane >= off) cr += t2; }
        float totr = __shfl(cr, 63);
        float wR = powf(10.f, (totr - cr) * rm) * rm;
        float rv = dvv * wR;
        #pragma unroll
        for (int off = 1; off < 64; off <<= 1) rv += __shfl_xor(rv, off);
        if (lane == 0) { lds[M_DG + 2] = lv; lds[M_DG + 3] = rv; }
    }
    __syncthreads();

    if (tid < 64) {       // pooled[c] = sum_r h[r][c] * rw[r]
        float p = 0.f;
        #pragma unroll 8
        for (int r2 = 0; r2 < 64; ++r2)
            p = fmaf(lds[BH + r2 * 65 + tid], lds[M_SD + r2], p);
        lds[M_NBU + tid] = p;
    }
    __syncthreads();
    if (tid < 4) {        // op logits
        float s = opc_b[tid];
        for (int c2 = 0; c2 < 64; ++c2) s = fmaf(lds[M_NBU + c2], opc_w[(c2 << 2) + tid], s);
        lds[M_DG + 4 + tid] = s;
    }
    __syncthreads();
    if (tid == 0) {       // hard argmax op select + fixed ops
        float l = lds[M_DG + 2], r = lds[M_DG + 3];
        float o0 = lds[M_DG + 4], o1 = lds[M_DG + 5], o2 = lds[M_DG + 6], o3 = lds[M_DG + 7];
        int op = 0; float bm = o0;
        if (o1 > bm) { bm = o1; op = 1; }
        if (o2 > bm) { bm = o2; op = 2; }
        if (o3 > bm) { bm = o3; op = 3; }
        float res, vl = 1.f;
        if (op == 0)      res = l + r;
        else if (op == 1) res = l - r;
        else if (op == 2) res = l * r;
        else { bool bad = fabsf(r) < 1e-6f; res = bad ? 0.f : (l / r); vl = bad ? 0.f : 1.f; }
        float rc = (res > 0.f) ? log1pf(res) : ((res < 0.f) ? -log1pf(-res) : 0.f);
        lds[M_DG + 0] = rc; lds[M_DG + 1] = vl;
        out[O_RES + b]   = res;
        out[O_VALID + b] = vl;
        out[O_LEFT + b]  = l;
        out[O_RIGHT + b] = r;
    }
    __syncthreads();
    if (tid < 64) {
        float rc = lds[M_DG + 0], vl = lds[M_DG + 1];
        out[O_REMB + (b << 6) + tid] = rc * res_w[tid] + vl * res_w[64 + tid] + res_b[tid];
        out[O_RW + (b << 6) + tid] = lds[M_SD + tid];
    }
    if (tid >= 64 && tid < 68) {
        int o = tid - 64;
        out[O_OPL + (b << 2) + o] = lds[M_DG + 4 + o];
    }
}

extern "C" void kernel_launch(void* const* d_in, const int* in_sizes, int n_in,
                              void* d_out, int out_size, void* d_ws, size_t ws_size,
                              hipStream_t stream)
{
    fsa_kernel<<<dim3(BATCH), dim3(256), 0, stream>>>(
        (const int*)d_in[0],
        (const float*)d_in[1],  (const float*)d_in[2],  (const float*)d_in[3],
        (const float*)d_in[4],  (const float*)d_in[5],  (const float*)d_in[6],  (const float*)d_in[7],
        (const float*)d_in[8],  (const float*)d_in[9],  (const float*)d_in[10], (const float*)d_in[11],
        (const float*)d_in[12], (const float*)d_in[13], (const float*)d_in[14], (const float*)d_in[15],
        (const float*)d_in[16], (const float*)d_in[17], (const float*)d_in[18], (const float*)d_in[19],
        (const float*)d_in[20], (const float*)d_in[21], (const float*)d_in[22], (const float*)d_in[23],
        (const float*)d_in[24], (const float*)d_in[25], (const float*)d_in[26], (const float*)d_in[27],
        (float*)d_out);
}